// Round 9
// baseline (361.787 us; speedup 1.0000x reference)
//
#include <hip/hip_runtime.h>

#define NNODES 100000
#define NEDGES 1600000
#define FIN 256
#define HDIM 256
#define CDIM 64
#define BN_EPS 1e-5f

// radix-CSR params
#define EPB 4096                         // edges per phase-1 block
#define NBLK ((NEDGES + EPB - 1) / EPB)  // 391
#define NSEGS ((NNODES + 255) / 256)     // 391 segments of 256 nodes
#define SEGCAP 4608                      // max edges per segment (mean 4096)
#define XBLK 1600                        // converter blocks fused into p1hist

typedef __attribute__((ext_vector_type(8))) short short8;
typedef __attribute__((ext_vector_type(8))) unsigned short ushort8_t;
typedef __attribute__((ext_vector_type(4))) float f32x4;

static __device__ __forceinline__ unsigned short f2bf(float f) {
  unsigned u = __float_as_uint(f);
  u += 0x7FFF + ((u >> 16) & 1);
  return (unsigned short)(u >> 16);
}
static __device__ __forceinline__ float bf2f(unsigned short h) {
  return __uint_as_float(((unsigned)h) << 16);
}

// ---------- CSR build via 2-phase LDS radix (no global atomics) ----------

// Phase 1a (fused): blocks < NBLK: per-block seg histogram + per-edge rank word;
// blocks >= NBLK: x -> bf16 convert (grid-stride).
__global__ __launch_bounds__(256) void p1hist_k(const int* __restrict__ dst,
                                                const float* __restrict__ x,
                                                unsigned* __restrict__ rank,
                                                int* __restrict__ bh,
                                                unsigned short* __restrict__ xbf) {
  __shared__ int lh[NSEGS];
  int b = blockIdx.x, t = threadIdx.x;
  if (b >= NBLK) {
    const int n4 = NNODES * FIN / 4;
    int i = (b - NBLK) * 256 + t;
    const int stride = XBLK * 256;
    for (; i < n4; i += stride) {
      float4 v = reinterpret_cast<const float4*>(x)[i];
      reinterpret_cast<ushort4*>(xbf)[i] =
          make_ushort4(f2bf(v.x), f2bf(v.y), f2bf(v.z), f2bf(v.w));
    }
    return;
  }
  for (int j = t; j < NSEGS; j += 256) lh[j] = 0;
  __syncthreads();
  int base = b * EPB;
  #pragma unroll
  for (int it = 0; it < EPB / 256; ++it) {
    int i = base + it * 256 + t;
    if (i < NEDGES) {
      int d = dst[i];
      int seg = d >> 8;
      int r = atomicAdd(&lh[seg], 1);
      rank[i] = ((unsigned)seg << 21) | ((unsigned)(d & 255) << 13) | (unsigned)r;
    }
  }
  __syncthreads();
  for (int j = t; j < NSEGS; j += 256) bh[j * NBLK + b] = lh[j];  // transposed
}

// Phase 1b (fused): blocks < NSEGS: per-seg exclusive prefix over blocks;
// blocks NSEGS..+HDIM: W1 col split; ..+CDIM: W2 col split; last: bn prep.
__global__ __launch_bounds__(512) void p1scan_k(
    const int* __restrict__ bh, int* __restrict__ rowpref, int* __restrict__ segtot,
    const float* __restrict__ W1, const float* __restrict__ W2,
    const float* __restrict__ b1, const float* __restrict__ gamma,
    const float* __restrict__ beta, const float* __restrict__ rm,
    const float* __restrict__ rv,
    unsigned short* __restrict__ w1thi, unsigned short* __restrict__ w1tlo,
    unsigned short* __restrict__ w2thi, unsigned short* __restrict__ w2tlo,
    float* __restrict__ bn_s, float* __restrict__ bn_t) {
  __shared__ int sm[512];
  int s = blockIdx.x, t = threadIdx.x;
  if (s >= NSEGS) {
    int j = s - NSEGS;
    if (j < HDIM) {  // W1 column j
      if (t < FIN) {
        float v = W1[(size_t)t * HDIM + j];
        unsigned short h = f2bf(v);
        w1thi[(size_t)j * FIN + t] = h;
        w1tlo[(size_t)j * FIN + t] = f2bf(v - bf2f(h));
      }
    } else if (j < HDIM + CDIM) {  // W2 column
      int n = j - HDIM;
      if (t < HDIM) {
        float v = W2[(size_t)t * CDIM + n];
        unsigned short h = f2bf(v);
        w2thi[(size_t)n * HDIM + t] = h;
        w2tlo[(size_t)n * HDIM + t] = f2bf(v - bf2f(h));
      }
    } else {  // bn prep
      if (t < HDIM) {
        float sc = gamma[t] * rsqrtf(rv[t] + BN_EPS);
        bn_s[t] = sc;
        bn_t[t] = (b1[t] - rm[t]) * sc + beta[t];
      }
    }
    return;
  }
  int v = (t < NBLK) ? bh[s * NBLK + t] : 0;
  sm[t] = v;
  __syncthreads();
  for (int off = 1; off < 512; off <<= 1) {
    int x = (t >= off) ? sm[t - off] : 0;
    __syncthreads();
    sm[t] += x;
    __syncthreads();
  }
  if (t < NBLK) rowpref[s * NBLK + t] = sm[t] - v;
  if (t == NBLK - 1) segtot[s] = sm[t];
}

__global__ __launch_bounds__(512) void segscan_k(const int* __restrict__ segtot,
                                                 int* __restrict__ segbase) {
  __shared__ int sm[512];
  int t = threadIdx.x;
  int v = (t < NSEGS) ? segtot[t] : 0;
  sm[t] = v;
  __syncthreads();
  for (int off = 1; off < 512; off <<= 1) {
    int x = (t >= off) ? sm[t - off] : 0;
    __syncthreads();
    sm[t] += x;
    __syncthreads();
  }
  if (t < NSEGS) segbase[t] = sm[t] - v;
  if (t == 0) segbase[NSEGS] = NEDGES;
}

// Phase 1c: seg-sort block's edges in LDS, then write coalesced runs.
// esort word = (src<<8) | (dst&255)
__global__ __launch_bounds__(512) void p1scat_k(const int* __restrict__ src,
                                                const unsigned* __restrict__ rank,
                                                const int* __restrict__ rowpref,
                                                const int* __restrict__ segbase,
                                                unsigned* __restrict__ esort) {
  __shared__ int lh[512];
  __shared__ int sc[512];
  __shared__ int O[NSEGS];
  __shared__ unsigned sorted[EPB];
  __shared__ unsigned short segslot[EPB];
  int b = blockIdx.x, t = threadIdx.x;
  int base = b * EPB;
  lh[t] = 0;
  __syncthreads();
  unsigned wv[EPB / 512];
  #pragma unroll
  for (int it = 0; it < EPB / 512; ++it) {
    int i = base + it * 512 + t;
    wv[it] = 0xFFFFFFFFu;
    if (i < NEDGES) {
      wv[it] = rank[i];
      atomicAdd(&lh[wv[it] >> 21], 1);
    }
  }
  __syncthreads();
  int v = lh[t];
  sc[t] = v;
  __syncthreads();
  for (int off = 1; off < 512; off <<= 1) {
    int x = (t >= off) ? sc[t - off] : 0;
    __syncthreads();
    sc[t] += x;
    __syncthreads();
  }
  int excl = sc[t] - v;
  __syncthreads();
  lh[t] = excl;
  if (t < NSEGS) O[t] = segbase[t] + rowpref[t * NBLK + b] - excl;
  __syncthreads();
  #pragma unroll
  for (int it = 0; it < EPB / 512; ++it) {
    int i = base + it * 512 + t;
    if (i < NEDGES) {
      unsigned w = wv[it];
      int seg = w >> 21;
      int r = w & 8191;
      int d8 = (w >> 13) & 255;
      int slot = lh[seg] + r;
      sorted[slot] = ((unsigned)src[i] << 8) | (unsigned)d8;
      segslot[slot] = (unsigned short)seg;
    }
  }
  __syncthreads();
  int nE = NEDGES - base;
  if (nE > EPB) nE = EPB;
  for (int j = t; j < nE; j += 512) esort[O[segslot[j]] + j] = sorted[j];
}

// Phase 2: per-seg counting sort by dst&255 in LDS, then per-node sort by src
// (ascending) so the agg kernels walk src monotonically -> L2 locality.
__global__ __launch_bounds__(256) void p2_k(const unsigned* __restrict__ esort,
                                            const int* __restrict__ segtot,
                                            const int* __restrict__ segbase,
                                            int* __restrict__ s_sorted,
                                            int* __restrict__ ptr,
                                            float* __restrict__ dinv) {
  __shared__ unsigned ebuf[SEGCAP];
  __shared__ unsigned short lrank[SEGCAP];
  __shared__ int outbuf[SEGCAP];
  __shared__ int lcnt[256];
  __shared__ int sm[256];
  __shared__ int nstart[256];
  int s = blockIdx.x, t = threadIdx.x;
  int base = segbase[s];
  int cntE = segtot[s];
  if (cntE > SEGCAP) cntE = SEGCAP;
  for (int j = t; j < cntE; j += 256) ebuf[j] = esort[base + j];
  lcnt[t] = 0;
  __syncthreads();
  for (int j = t; j < cntE; j += 256) {
    int d8 = ebuf[j] & 255;
    lrank[j] = (unsigned short)atomicAdd(&lcnt[d8], 1);
  }
  __syncthreads();
  int v = lcnt[t];
  sm[t] = v;
  __syncthreads();
  for (int off = 1; off < 256; off <<= 1) {
    int x = (t >= off) ? sm[t - off] : 0;
    __syncthreads();
    sm[t] += x;
    __syncthreads();
  }
  nstart[t] = sm[t] - v;
  int node = s * 256 + t;
  if (node < NNODES) {
    ptr[node] = base + sm[t] - v;
    dinv[node] = rsqrtf((float)v + 1.0f);
  }
  __syncthreads();
  for (int j = t; j < cntE; j += 256) {
    unsigned w = ebuf[j];
    outbuf[nstart[w & 255] + lrank[j]] = (int)(w >> 8);
  }
  __syncthreads();
  // per-node insertion sort by src (thread t owns node t's slice)
  {
    int st = nstart[t];
    for (int a = 1; a < v; ++a) {
      int key = outbuf[st + a];
      int bq = a - 1;
      while (bq >= 0 && outbuf[st + bq] > key) {
        outbuf[st + bq + 1] = outbuf[st + bq];
        --bq;
      }
      outbuf[st + bq + 1] = key;
    }
  }
  __syncthreads();
  for (int j = t; j < cntE; j += 256) s_sorted[base + j] = outbuf[j];
  if (s == 0 && t == 0) ptr[NNODES] = NEDGES;
}

// ---------- agg_x: xhat = A_norm * x. Half-wave per edge, ushort8 (16B) per lane. ----------

__global__ __launch_bounds__(256) void agg_x_k(
    const int* __restrict__ ptr, const int* __restrict__ ss,
    const float* __restrict__ dinv, const unsigned short* __restrict__ xbf,
    unsigned short* __restrict__ xhHi, int n) {
  int w = threadIdx.x >> 6;
  int lane = threadIdx.x & 63;
  int i = blockIdx.x * 4 + w;
  if (i >= n) return;
  int sub = lane >> 5;       // 0: even edges, 1: odd edges
  int f8 = (lane & 31) * 8;  // 8 features per lane
  int beg = ptr[i], end = ptr[i + 1];
  float di = dinv[i];
  float a[8] = {};
  int e = beg;
  for (; e + 8 <= end; e += 8) {
    int s0 = ss[e + sub], s1 = ss[e + 2 + sub], s2 = ss[e + 4 + sub], s3 = ss[e + 6 + sub];
    float c0 = dinv[s0], c1 = dinv[s1], c2 = dinv[s2], c3 = dinv[s3];
    ushort8_t v0 = *reinterpret_cast<const ushort8_t*>(xbf + (size_t)s0 * FIN + f8);
    ushort8_t v1 = *reinterpret_cast<const ushort8_t*>(xbf + (size_t)s1 * FIN + f8);
    ushort8_t v2 = *reinterpret_cast<const ushort8_t*>(xbf + (size_t)s2 * FIN + f8);
    ushort8_t v3 = *reinterpret_cast<const ushort8_t*>(xbf + (size_t)s3 * FIN + f8);
    #pragma unroll
    for (int k = 0; k < 8; ++k)
      a[k] += c0 * bf2f(v0[k]) + c1 * bf2f(v1[k]) + c2 * bf2f(v2[k]) + c3 * bf2f(v3[k]);
  }
  for (; e < end; e += 2) {
    int idx = e + sub;
    if (idx < end) {
      int s = ss[idx];
      float c = dinv[s];
      ushort8_t v = *reinterpret_cast<const ushort8_t*>(xbf + (size_t)s * FIN + f8);
      #pragma unroll
      for (int k = 0; k < 8; ++k) a[k] += c * bf2f(v[k]);
    }
  }
  #pragma unroll
  for (int k = 0; k < 8; ++k) a[k] += __shfl_xor(a[k], 32);
  if (sub == 0) {
    ushort8_t vs = *reinterpret_cast<const ushort8_t*>(xbf + (size_t)i * FIN + f8);
    float di2 = di * di;
    ushort8_t o;
    #pragma unroll
    for (int k = 0; k < 8; ++k) o[k] = f2bf(a[k] * di + bf2f(vs[k]) * di2);
    *reinterpret_cast<ushort8_t*>(xhHi + (size_t)i * FIN + f8) = o;
  }
}

// ---------- split-bf16 MFMA GEMM: C = A*Bt^T. BM=128, BK=64. ----------
// ALO: 3-term (AhiBhi+AhiBlo+AloBhi); else 2-term (AhiBhi+AhiBlo).
// EPI=1: O1 = bf16(relu(v*bn_s+bn_t))  (GEMM1)
// EPI=2: C fp32, O1 = bf16(v)          (GEMM2)

template <int BN, int EPI, bool ALO>
__global__ __launch_bounds__(256) void gemm_split_k(
    const unsigned short* __restrict__ Ahi, const unsigned short* __restrict__ Alo,
    const unsigned short* __restrict__ Bhi, const unsigned short* __restrict__ Blo,
    float* __restrict__ C, unsigned short* __restrict__ O1,
    const float* __restrict__ bn_s, const float* __restrict__ bn_t,
    int M, int N, int K) {
  constexpr int WC = BN / 32;
  constexpr int ASZ = (ALO ? 2 : 1) * 128 * 64;
  __shared__ unsigned short smem[ASZ + 2 * BN * 64];
  unsigned short* aHi = smem;
  unsigned short* aLo = smem + 128 * 64;  // only if ALO
  unsigned short* bHi = smem + ASZ;
  unsigned short* bLo = bHi + BN * 64;

  const int tid = threadIdx.x;
  const int w = tid >> 6;
  const int lane = tid & 63;
  const int wr = w >> 1, wc = w & 1;
  const int row0 = blockIdx.x * 128;
  const int col0 = blockIdx.y * BN;

  f32x4 acc[4][WC];
  #pragma unroll
  for (int mi = 0; mi < 4; ++mi)
    #pragma unroll
    for (int ni = 0; ni < WC; ++ni) {
      f32x4 z = {0.f, 0.f, 0.f, 0.f};
      acc[mi][ni] = z;
    }

  auto stage = [&](const unsigned short* G, unsigned short* Ld, int rows, int gr0,
                   int maxRow, int k0) {
    for (int i = 0; i < rows / 32; ++i) {
      int chunk = i * 256 + tid;
      int r = chunk >> 3;
      int c = chunk & 7;
      int cs = c ^ (r & 7);
      int gr = gr0 + r;
      if (gr > maxRow) gr = maxRow;
      const unsigned short* gp = G + (size_t)gr * K + k0 + cs * 8;
      unsigned short* lp = Ld + (i * 256 + w * 64) * 8;
      __builtin_amdgcn_global_load_lds((const __attribute__((address_space(1))) void*)gp,
                                       (__attribute__((address_space(3))) void*)lp, 16, 0, 0);
    }
  };

  for (int k0 = 0; k0 < K; k0 += 64) {
    stage(Ahi, aHi, 128, row0, M - 1, k0);
    if constexpr (ALO) stage(Alo, aLo, 128, row0, M - 1, k0);
    stage(Bhi, bHi, BN, col0, N - 1, k0);
    stage(Blo, bLo, BN, col0, N - 1, k0);
    __syncthreads();
    #pragma unroll
    for (int kk = 0; kk < 2; ++kk) {
      short8 ah[4], al[4], bh[WC], bl[WC];
      #pragma unroll
      for (int mi = 0; mi < 4; ++mi) {
        int lr = wr * 64 + mi * 16 + (lane & 15);
        int slot = (kk * 4 + (lane >> 4)) ^ (lr & 7);
        int eo = lr * 64 + slot * 8;
        ah[mi] = *reinterpret_cast<const short8*>(aHi + eo);
        if constexpr (ALO) al[mi] = *reinterpret_cast<const short8*>(aLo + eo);
      }
      #pragma unroll
      for (int ni = 0; ni < WC; ++ni) {
        int lr = wc * (BN / 2) + ni * 16 + (lane & 15);
        int slot = (kk * 4 + (lane >> 4)) ^ (lr & 7);
        int eo = lr * 64 + slot * 8;
        bh[ni] = *reinterpret_cast<const short8*>(bHi + eo);
        bl[ni] = *reinterpret_cast<const short8*>(bLo + eo);
      }
      #pragma unroll
      for (int mi = 0; mi < 4; ++mi)
        #pragma unroll
        for (int ni = 0; ni < WC; ++ni) {
          acc[mi][ni] = __builtin_amdgcn_mfma_f32_16x16x32_bf16(ah[mi], bh[ni], acc[mi][ni], 0, 0, 0);
          acc[mi][ni] = __builtin_amdgcn_mfma_f32_16x16x32_bf16(ah[mi], bl[ni], acc[mi][ni], 0, 0, 0);
          if constexpr (ALO)
            acc[mi][ni] = __builtin_amdgcn_mfma_f32_16x16x32_bf16(al[mi], bh[ni], acc[mi][ni], 0, 0, 0);
        }
    }
    __syncthreads();
  }

  // C/D layout: col = lane&15, row = (lane>>4)*4 + r
  #pragma unroll
  for (int ni = 0; ni < WC; ++ni) {
    int cc = col0 + wc * (BN / 2) + ni * 16 + (lane & 15);
    float sc = 0.f, tc = 0.f;
    if (EPI == 1) { sc = bn_s[cc]; tc = bn_t[cc]; }
    #pragma unroll
    for (int mi = 0; mi < 4; ++mi) {
      int rbase = row0 + wr * 64 + mi * 16 + (lane >> 4) * 4;
      #pragma unroll
      for (int r = 0; r < 4; ++r) {
        int rr = rbase + r;
        if (rr < M) {
          float v = acc[mi][ni][r];
          if (EPI == 1) {
            v = fmaxf(v * sc + tc, 0.f);
            O1[(size_t)rr * N + cc] = f2bf(v);
          } else {
            C[(size_t)rr * N + cc] = v;
            O1[(size_t)rr * N + cc] = f2bf(v);
          }
        }
      }
    }
  }
}

// ---------- agg2: out = A_norm*h2 + b2. Quarter-wave per edge, ushort4 per lane. ----------

__global__ __launch_bounds__(256) void agg2_k(
    const int* __restrict__ ptr, const int* __restrict__ ss,
    const float* __restrict__ dinv, const float* __restrict__ h2,
    const unsigned short* __restrict__ h2bf, const float* __restrict__ b2,
    float* __restrict__ out, int n) {
  int w = threadIdx.x >> 6;
  int lane = threadIdx.x & 63;
  int i = blockIdx.x * 4 + w;
  if (i >= n) return;
  int sub = lane >> 4;       // 0..3: edge phase
  int f4 = (lane & 15) * 4;  // 4 features per lane
  int beg = ptr[i], end = ptr[i + 1];
  float di = dinv[i];
  float a[4] = {};
  int e = beg;
  for (; e + 16 <= end; e += 16) {
    int s0 = ss[e + sub], s1 = ss[e + 4 + sub], s2 = ss[e + 8 + sub], s3 = ss[e + 12 + sub];
    float c0 = dinv[s0], c1 = dinv[s1], c2 = dinv[s2], c3 = dinv[s3];
    ushort4 v0 = *reinterpret_cast<const ushort4*>(h2bf + (size_t)s0 * CDIM + f4);
    ushort4 v1 = *reinterpret_cast<const ushort4*>(h2bf + (size_t)s1 * CDIM + f4);
    ushort4 v2 = *reinterpret_cast<const ushort4*>(h2bf + (size_t)s2 * CDIM + f4);
    ushort4 v3 = *reinterpret_cast<const ushort4*>(h2bf + (size_t)s3 * CDIM + f4);
    a[0] += c0 * bf2f(v0.x) + c1 * bf2f(v1.x) + c2 * bf2f(v2.x) + c3 * bf2f(v3.x);
    a[1] += c0 * bf2f(v0.y) + c1 * bf2f(v1.y) + c2 * bf2f(v2.y) + c3 * bf2f(v3.y);
    a[2] += c0 * bf2f(v0.z) + c1 * bf2f(v1.z) + c2 * bf2f(v2.z) + c3 * bf2f(v3.z);
    a[3] += c0 * bf2f(v0.w) + c1 * bf2f(v1.w) + c2 * bf2f(v2.w) + c3 * bf2f(v3.w);
  }
  for (; e < end; e += 4) {
    int idx = e + sub;
    if (idx < end) {
      int s = ss[idx];
      float c = dinv[s];
      ushort4 v = *reinterpret_cast<const ushort4*>(h2bf + (size_t)s * CDIM + f4);
      a[0] += c * bf2f(v.x); a[1] += c * bf2f(v.y);
      a[2] += c * bf2f(v.z); a[3] += c * bf2f(v.w);
    }
  }
  #pragma unroll
  for (int k = 0; k < 4; ++k) {
    a[k] += __shfl_xor(a[k], 16);
    a[k] += __shfl_xor(a[k], 32);
  }
  if (sub == 0) {
    float4 self = *reinterpret_cast<const float4*>(h2 + (size_t)i * CDIM + f4);
    float4 vb2 = *reinterpret_cast<const float4*>(b2 + f4);
    float di2 = di * di;
    float4 o;
    o.x = a[0] * di + self.x * di2 + vb2.x;
    o.y = a[1] * di + self.y * di2 + vb2.y;
    o.z = a[2] * di + self.z * di2 + vb2.z;
    o.w = a[3] * di + self.w * di2 + vb2.w;
    *reinterpret_cast<float4*>(out + (size_t)i * CDIM + f4) = o;
  }
}

extern "C" void kernel_launch(void* const* d_in, const int* in_sizes, int n_in,
                              void* d_out, int out_size, void* d_ws, size_t ws_size,
                              hipStream_t stream) {
  const float* x     = (const float*)d_in[0];
  const int*   ei    = (const int*)d_in[1];
  const float* W1    = (const float*)d_in[2];
  const float* b1    = (const float*)d_in[3];
  const float* gamma = (const float*)d_in[4];
  const float* beta  = (const float*)d_in[5];
  const float* rm    = (const float*)d_in[6];
  const float* rv    = (const float*)d_in[7];
  const float* W2    = (const float*)d_in[8];
  const float* b2    = (const float*)d_in[9];
  float* out = (float*)d_out;

  const int* src = ei;
  const int* dst = ei + NEDGES;

  char* ws = (char*)d_ws;
  auto alloc = [&](size_t bytes) {
    void* p = ws;
    ws += (bytes + 255) & ~(size_t)255;
    return p;
  };
  unsigned* rank    = (unsigned*)alloc((size_t)NEDGES * 4);
  unsigned* esort   = (unsigned*)alloc((size_t)NEDGES * 4);
  int*   bh       = (int*)alloc((size_t)NSEGS * NBLK * 4);
  int*   rowpref  = (int*)alloc((size_t)NSEGS * NBLK * 4);
  int*   segtot   = (int*)alloc((size_t)NSEGS * 4);
  int*   segbase  = (int*)alloc(((size_t)NSEGS + 1) * 4);
  int*   ptr      = (int*)alloc(((size_t)NNODES + 1) * 4);
  float* dinv     = (float*)alloc((size_t)NNODES * 4);
  int*   s_sorted = (int*)alloc((size_t)NEDGES * 4);
  unsigned short* xbf    = (unsigned short*)alloc((size_t)NNODES * FIN * 2);  // -> houtHi
  unsigned short* xhHi   = (unsigned short*)alloc((size_t)NNODES * FIN * 2);  // -> h2 (fp32)
  unsigned short* h2bf   = (unsigned short*)alloc((size_t)NNODES * CDIM * 2);
  unsigned short* w1thi  = (unsigned short*)alloc((size_t)HDIM * FIN * 2);
  unsigned short* w1tlo  = (unsigned short*)alloc((size_t)HDIM * FIN * 2);
  unsigned short* w2thi  = (unsigned short*)alloc((size_t)CDIM * HDIM * 2);
  unsigned short* w2tlo  = (unsigned short*)alloc((size_t)CDIM * HDIM * 2);
  float* bn_s = (float*)alloc(HDIM * 4);
  float* bn_t = (float*)alloc(HDIM * 4);

  unsigned short* houtHi = xbf;           // alias: xbf dead after agg_x
  float*          h2     = (float*)xhHi;  // alias: xhat dead after GEMM1 (25.6MB < 51.2MB)

  // CSR build (convert + weight-split fused into the low-occupancy passes)
  p1hist_k<<<NBLK + XBLK, 256, 0, stream>>>(dst, x, rank, bh, xbf);
  p1scan_k<<<NSEGS + HDIM + CDIM + 1, 512, 0, stream>>>(
      bh, rowpref, segtot, W1, W2, b1, gamma, beta, rm, rv,
      w1thi, w1tlo, w2thi, w2tlo, bn_s, bn_t);
  segscan_k<<<1, 512, 0, stream>>>(segtot, segbase);
  p1scat_k<<<NBLK, 512, 0, stream>>>(src, rank, rowpref, segbase, esort);
  p2_k<<<NSEGS, 256, 0, stream>>>(esort, segtot, segbase, s_sorted, ptr, dinv);

  // layer 1 reordered: xhat = A_norm*x (bf16), hout = relu(BN(xhat@W1+b1)) in GEMM epilogue
  agg_x_k<<<(NNODES + 3) / 4, 256, 0, stream>>>(ptr, s_sorted, dinv, xbf, xhHi, NNODES);
  gemm_split_k<128, 1, false><<<dim3((NNODES + 127) / 128, HDIM / 128), 256, 0, stream>>>(
      xhHi, nullptr, w1thi, w1tlo, nullptr, houtHi, bn_s, bn_t, NNODES, HDIM, FIN);

  // layer 2: h2 = hout@W2 (2-term), out = A_norm*h2 + b2
  gemm_split_k<64, 2, false><<<dim3((NNODES + 127) / 128, 1), 256, 0, stream>>>(
      houtHi, nullptr, w2thi, w2tlo, h2, h2bf, nullptr, nullptr, NNODES, CDIM, HDIM);
  agg2_k<<<(NNODES + 3) / 4, 256, 0, stream>>>(ptr, s_sorted, dinv, h2, h2bf, b2, out, NNODES);
}

// Round 10
// 313.596 us; speedup vs baseline: 1.1537x; 1.1537x over previous
//
#include <hip/hip_runtime.h>

#define NNODES 100000
#define NEDGES 1600000
#define FIN 256
#define HDIM 256
#define CDIM 64
#define BN_EPS 1e-5f

// radix-CSR params
#define EPB 4096                         // edges per phase-1 block
#define NBLK ((NEDGES + EPB - 1) / EPB)  // 391
#define NSEGS ((NNODES + 255) / 256)     // 391 segments of 256 nodes
#define SEGCAP 4608                      // max edges per segment (mean 4096)
#define XBLK 1600                        // converter blocks fused into p1hist

typedef __attribute__((ext_vector_type(8))) short short8;
typedef __attribute__((ext_vector_type(8))) unsigned short ushort8_t;
typedef __attribute__((ext_vector_type(4))) float f32x4;

static __device__ __forceinline__ unsigned short f2bf(float f) {
  unsigned u = __float_as_uint(f);
  u += 0x7FFF + ((u >> 16) & 1);
  return (unsigned short)(u >> 16);
}
static __device__ __forceinline__ float bf2f(unsigned short h) {
  return __uint_as_float(((unsigned)h) << 16);
}

// ---------- CSR build via 2-phase LDS radix (no global atomics) ----------

// Phase 1a (fused): blocks < NBLK: per-block seg histogram;
// blocks >= NBLK: x -> bf16 convert (grid-stride).
__global__ __launch_bounds__(256) void p1hist_k(const int* __restrict__ dst,
                                                const float* __restrict__ x,
                                                int* __restrict__ bh,
                                                unsigned short* __restrict__ xbf) {
  __shared__ int lh[NSEGS];
  int b = blockIdx.x, t = threadIdx.x;
  if (b >= NBLK) {
    const int n4 = NNODES * FIN / 4;
    int i = (b - NBLK) * 256 + t;
    const int stride = XBLK * 256;
    for (; i < n4; i += stride) {
      float4 v = reinterpret_cast<const float4*>(x)[i];
      reinterpret_cast<ushort4*>(xbf)[i] =
          make_ushort4(f2bf(v.x), f2bf(v.y), f2bf(v.z), f2bf(v.w));
    }
    return;
  }
  for (int j = t; j < NSEGS; j += 256) lh[j] = 0;
  __syncthreads();
  int base = b * EPB;
  #pragma unroll
  for (int it = 0; it < EPB / 256; ++it) {
    int i = base + it * 256 + t;
    if (i < NEDGES) atomicAdd(&lh[dst[i] >> 8], 1);
  }
  __syncthreads();
  for (int j = t; j < NSEGS; j += 256) bh[j * NBLK + b] = lh[j];  // transposed
}

// Phase 1b (fused): blocks < NSEGS: per-seg exclusive prefix over blocks;
// blocks NSEGS..+HDIM: W1 col split; ..+CDIM: W2 col split; last: bn prep.
__global__ __launch_bounds__(512) void p1scan_k(
    const int* __restrict__ bh, int* __restrict__ rowpref, int* __restrict__ segtot,
    const float* __restrict__ W1, const float* __restrict__ W2,
    const float* __restrict__ b1, const float* __restrict__ gamma,
    const float* __restrict__ beta, const float* __restrict__ rm,
    const float* __restrict__ rv,
    unsigned short* __restrict__ w1thi, unsigned short* __restrict__ w1tlo,
    unsigned short* __restrict__ w2thi, unsigned short* __restrict__ w2tlo,
    float* __restrict__ bn_s, float* __restrict__ bn_t) {
  __shared__ int sm[512];
  int s = blockIdx.x, t = threadIdx.x;
  if (s >= NSEGS) {
    int j = s - NSEGS;
    if (j < HDIM) {  // W1 column j
      if (t < FIN) {
        float v = W1[(size_t)t * HDIM + j];
        unsigned short h = f2bf(v);
        w1thi[(size_t)j * FIN + t] = h;
        w1tlo[(size_t)j * FIN + t] = f2bf(v - bf2f(h));
      }
    } else if (j < HDIM + CDIM) {  // W2 column
      int n = j - HDIM;
      if (t < HDIM) {
        float v = W2[(size_t)t * CDIM + n];
        unsigned short h = f2bf(v);
        w2thi[(size_t)n * HDIM + t] = h;
        w2tlo[(size_t)n * HDIM + t] = f2bf(v - bf2f(h));
      }
    } else {  // bn prep
      if (t < HDIM) {
        float sc = gamma[t] * rsqrtf(rv[t] + BN_EPS);
        bn_s[t] = sc;
        bn_t[t] = (b1[t] - rm[t]) * sc + beta[t];
      }
    }
    return;
  }
  int v = (t < NBLK) ? bh[s * NBLK + t] : 0;
  sm[t] = v;
  __syncthreads();
  for (int off = 1; off < 512; off <<= 1) {
    int x = (t >= off) ? sm[t - off] : 0;
    __syncthreads();
    sm[t] += x;
    __syncthreads();
  }
  if (t < NBLK) rowpref[s * NBLK + t] = sm[t] - v;
  if (t == NBLK - 1) segtot[s] = sm[t];
}

__global__ __launch_bounds__(512) void segscan_k(const int* __restrict__ segtot,
                                                 int* __restrict__ segbase) {
  __shared__ int sm[512];
  int t = threadIdx.x;
  int v = (t < NSEGS) ? segtot[t] : 0;
  sm[t] = v;
  __syncthreads();
  for (int off = 1; off < 512; off <<= 1) {
    int x = (t >= off) ? sm[t - off] : 0;
    __syncthreads();
    sm[t] += x;
    __syncthreads();
  }
  if (t < NSEGS) segbase[t] = sm[t] - v;
  if (t == 0) segbase[NSEGS] = NEDGES;
}

// Phase 1c: seg-sort block's edges in LDS (ranks self-generated), write coalesced runs.
// esort word = (src<<8) | (dst&255)
__global__ __launch_bounds__(512) void p1scat_k(const int* __restrict__ src,
                                                const int* __restrict__ dst,
                                                const int* __restrict__ rowpref,
                                                const int* __restrict__ segbase,
                                                unsigned* __restrict__ esort) {
  __shared__ int lh[512];
  __shared__ int sc[512];
  __shared__ int O[NSEGS];
  __shared__ unsigned sorted[EPB];
  __shared__ unsigned short segslot[EPB];
  int b = blockIdx.x, t = threadIdx.x;
  int base = b * EPB;
  lh[t] = 0;
  __syncthreads();
  unsigned wv[EPB / 512];
  #pragma unroll
  for (int it = 0; it < EPB / 512; ++it) {
    int i = base + it * 512 + t;
    wv[it] = 0xFFFFFFFFu;
    if (i < NEDGES) {
      int d = dst[i];
      int seg = d >> 8;
      int r = atomicAdd(&lh[seg], 1);
      wv[it] = ((unsigned)seg << 21) | ((unsigned)(d & 255) << 13) | (unsigned)r;
    }
  }
  __syncthreads();
  int v = lh[t];
  sc[t] = v;
  __syncthreads();
  for (int off = 1; off < 512; off <<= 1) {
    int x = (t >= off) ? sc[t - off] : 0;
    __syncthreads();
    sc[t] += x;
    __syncthreads();
  }
  int excl = sc[t] - v;
  __syncthreads();
  lh[t] = excl;
  if (t < NSEGS) O[t] = segbase[t] + rowpref[t * NBLK + b] - excl;
  __syncthreads();
  #pragma unroll
  for (int it = 0; it < EPB / 512; ++it) {
    int i = base + it * 512 + t;
    if (i < NEDGES) {
      unsigned w = wv[it];
      int seg = w >> 21;
      int r = w & 8191;
      int d8 = (w >> 13) & 255;
      int slot = lh[seg] + r;
      sorted[slot] = ((unsigned)src[i] << 8) | (unsigned)d8;
      segslot[slot] = (unsigned short)seg;
    }
  }
  __syncthreads();
  int nE = NEDGES - base;
  if (nE > EPB) nE = EPB;
  for (int j = t; j < nE; j += 512) esort[O[segslot[j]] + j] = sorted[j];
}

// Phase 2: per-seg counting sort by dst&255 in LDS; emit s_sorted/ptr/dinv coalesced.
__global__ __launch_bounds__(256) void p2_k(const unsigned* __restrict__ esort,
                                            const int* __restrict__ segtot,
                                            const int* __restrict__ segbase,
                                            int* __restrict__ s_sorted,
                                            int* __restrict__ ptr,
                                            float* __restrict__ dinv) {
  __shared__ unsigned ebuf[SEGCAP];
  __shared__ unsigned short lrank[SEGCAP];
  __shared__ int outbuf[SEGCAP];
  __shared__ int lcnt[256];
  __shared__ int sm[256];
  __shared__ int nstart[256];
  int s = blockIdx.x, t = threadIdx.x;
  int base = segbase[s];
  int cntE = segtot[s];
  if (cntE > SEGCAP) cntE = SEGCAP;
  for (int j = t; j < cntE; j += 256) ebuf[j] = esort[base + j];
  lcnt[t] = 0;
  __syncthreads();
  for (int j = t; j < cntE; j += 256) {
    int d8 = ebuf[j] & 255;
    lrank[j] = (unsigned short)atomicAdd(&lcnt[d8], 1);
  }
  __syncthreads();
  int v = lcnt[t];
  sm[t] = v;
  __syncthreads();
  for (int off = 1; off < 256; off <<= 1) {
    int x = (t >= off) ? sm[t - off] : 0;
    __syncthreads();
    sm[t] += x;
    __syncthreads();
  }
  nstart[t] = sm[t] - v;
  int node = s * 256 + t;
  if (node < NNODES) {
    ptr[node] = base + sm[t] - v;
    dinv[node] = rsqrtf((float)v + 1.0f);
  }
  __syncthreads();
  for (int j = t; j < cntE; j += 256) {
    unsigned w = ebuf[j];
    outbuf[nstart[w & 255] + lrank[j]] = (int)(w >> 8);
  }
  __syncthreads();
  for (int j = t; j < cntE; j += 256) s_sorted[base + j] = outbuf[j];
  if (s == 0 && t == 0) ptr[NNODES] = NEDGES;
}

// ---------- agg_x: xhat = A_norm * x. Half-wave per edge, ushort8 (16B) per lane. ----------

__global__ __launch_bounds__(256) void agg_x_k(
    const int* __restrict__ ptr, const int* __restrict__ ss,
    const float* __restrict__ dinv, const unsigned short* __restrict__ xbf,
    unsigned short* __restrict__ xhHi, int n) {
  int w = threadIdx.x >> 6;
  int lane = threadIdx.x & 63;
  int i = blockIdx.x * 4 + w;
  if (i >= n) return;
  int sub = lane >> 5;       // 0: even edges, 1: odd edges
  int f8 = (lane & 31) * 8;  // 8 features per lane
  int beg = ptr[i], end = ptr[i + 1];
  float di = dinv[i];
  float a[8] = {};
  int e = beg;
  for (; e + 8 <= end; e += 8) {
    int s0 = ss[e + sub], s1 = ss[e + 2 + sub], s2 = ss[e + 4 + sub], s3 = ss[e + 6 + sub];
    float c0 = dinv[s0], c1 = dinv[s1], c2 = dinv[s2], c3 = dinv[s3];
    ushort8_t v0 = *reinterpret_cast<const ushort8_t*>(xbf + (size_t)s0 * FIN + f8);
    ushort8_t v1 = *reinterpret_cast<const ushort8_t*>(xbf + (size_t)s1 * FIN + f8);
    ushort8_t v2 = *reinterpret_cast<const ushort8_t*>(xbf + (size_t)s2 * FIN + f8);
    ushort8_t v3 = *reinterpret_cast<const ushort8_t*>(xbf + (size_t)s3 * FIN + f8);
    #pragma unroll
    for (int k = 0; k < 8; ++k)
      a[k] += c0 * bf2f(v0[k]) + c1 * bf2f(v1[k]) + c2 * bf2f(v2[k]) + c3 * bf2f(v3[k]);
  }
  for (; e < end; e += 2) {
    int idx = e + sub;
    if (idx < end) {
      int s = ss[idx];
      float c = dinv[s];
      ushort8_t v = *reinterpret_cast<const ushort8_t*>(xbf + (size_t)s * FIN + f8);
      #pragma unroll
      for (int k = 0; k < 8; ++k) a[k] += c * bf2f(v[k]);
    }
  }
  #pragma unroll
  for (int k = 0; k < 8; ++k) a[k] += __shfl_xor(a[k], 32);
  if (sub == 0) {
    ushort8_t vs = *reinterpret_cast<const ushort8_t*>(xbf + (size_t)i * FIN + f8);
    float di2 = di * di;
    ushort8_t o;
    #pragma unroll
    for (int k = 0; k < 8; ++k) o[k] = f2bf(a[k] * di + bf2f(vs[k]) * di2);
    *reinterpret_cast<ushort8_t*>(xhHi + (size_t)i * FIN + f8) = o;
  }
}

// ---------- split-bf16 MFMA GEMM: C = A*Bt^T. BM=128, BK=64. 2-term. ----------
// EPI=1: O1 = bf16(relu(v*bn_s+bn_t))  (GEMM1)
// EPI=2: O1 = bf16(v)                  (GEMM2)

template <int BN, int EPI>
__global__ __launch_bounds__(256) void gemm_split_k(
    const unsigned short* __restrict__ Ahi,
    const unsigned short* __restrict__ Bhi, const unsigned short* __restrict__ Blo,
    unsigned short* __restrict__ O1,
    const float* __restrict__ bn_s, const float* __restrict__ bn_t,
    int M, int N, int K) {
  constexpr int WC = BN / 32;
  __shared__ unsigned short smem[128 * 64 + 2 * BN * 64];
  unsigned short* aHi = smem;
  unsigned short* bHi = smem + 128 * 64;
  unsigned short* bLo = bHi + BN * 64;

  const int tid = threadIdx.x;
  const int w = tid >> 6;
  const int lane = tid & 63;
  const int wr = w >> 1, wc = w & 1;
  const int row0 = blockIdx.x * 128;
  const int col0 = blockIdx.y * BN;

  f32x4 acc[4][WC];
  #pragma unroll
  for (int mi = 0; mi < 4; ++mi)
    #pragma unroll
    for (int ni = 0; ni < WC; ++ni) {
      f32x4 z = {0.f, 0.f, 0.f, 0.f};
      acc[mi][ni] = z;
    }

  auto stage = [&](const unsigned short* G, unsigned short* Ld, int rows, int gr0,
                   int maxRow, int k0) {
    for (int i = 0; i < rows / 32; ++i) {
      int chunk = i * 256 + tid;
      int r = chunk >> 3;
      int c = chunk & 7;
      int cs = c ^ (r & 7);
      int gr = gr0 + r;
      if (gr > maxRow) gr = maxRow;
      const unsigned short* gp = G + (size_t)gr * K + k0 + cs * 8;
      unsigned short* lp = Ld + (i * 256 + w * 64) * 8;
      __builtin_amdgcn_global_load_lds((const __attribute__((address_space(1))) void*)gp,
                                       (__attribute__((address_space(3))) void*)lp, 16, 0, 0);
    }
  };

  for (int k0 = 0; k0 < K; k0 += 64) {
    stage(Ahi, aHi, 128, row0, M - 1, k0);
    stage(Bhi, bHi, BN, col0, N - 1, k0);
    stage(Blo, bLo, BN, col0, N - 1, k0);
    __syncthreads();
    #pragma unroll
    for (int kk = 0; kk < 2; ++kk) {
      short8 ah[4], bh[WC], bl[WC];
      #pragma unroll
      for (int mi = 0; mi < 4; ++mi) {
        int lr = wr * 64 + mi * 16 + (lane & 15);
        int slot = (kk * 4 + (lane >> 4)) ^ (lr & 7);
        int eo = lr * 64 + slot * 8;
        ah[mi] = *reinterpret_cast<const short8*>(aHi + eo);
      }
      #pragma unroll
      for (int ni = 0; ni < WC; ++ni) {
        int lr = wc * (BN / 2) + ni * 16 + (lane & 15);
        int slot = (kk * 4 + (lane >> 4)) ^ (lr & 7);
        int eo = lr * 64 + slot * 8;
        bh[ni] = *reinterpret_cast<const short8*>(bHi + eo);
        bl[ni] = *reinterpret_cast<const short8*>(bLo + eo);
      }
      #pragma unroll
      for (int mi = 0; mi < 4; ++mi)
        #pragma unroll
        for (int ni = 0; ni < WC; ++ni) {
          acc[mi][ni] = __builtin_amdgcn_mfma_f32_16x16x32_bf16(ah[mi], bh[ni], acc[mi][ni], 0, 0, 0);
          acc[mi][ni] = __builtin_amdgcn_mfma_f32_16x16x32_bf16(ah[mi], bl[ni], acc[mi][ni], 0, 0, 0);
        }
    }
    __syncthreads();
  }

  // C/D layout: col = lane&15, row = (lane>>4)*4 + r
  #pragma unroll
  for (int ni = 0; ni < WC; ++ni) {
    int cc = col0 + wc * (BN / 2) + ni * 16 + (lane & 15);
    float sc = 0.f, tc = 0.f;
    if (EPI == 1) { sc = bn_s[cc]; tc = bn_t[cc]; }
    #pragma unroll
    for (int mi = 0; mi < 4; ++mi) {
      int rbase = row0 + wr * 64 + mi * 16 + (lane >> 4) * 4;
      #pragma unroll
      for (int r = 0; r < 4; ++r) {
        int rr = rbase + r;
        if (rr < M) {
          float v = acc[mi][ni][r];
          if (EPI == 1) v = fmaxf(v * sc + tc, 0.f);
          O1[(size_t)rr * N + cc] = f2bf(v);
        }
      }
    }
  }
}

// ---------- agg2: out = A_norm*h2 + b2. Quarter-wave per edge, ushort4 per lane. ----------

__global__ __launch_bounds__(256) void agg2_k(
    const int* __restrict__ ptr, const int* __restrict__ ss,
    const float* __restrict__ dinv,
    const unsigned short* __restrict__ h2bf, const float* __restrict__ b2,
    float* __restrict__ out, int n) {
  int w = threadIdx.x >> 6;
  int lane = threadIdx.x & 63;
  int i = blockIdx.x * 4 + w;
  if (i >= n) return;
  int sub = lane >> 4;       // 0..3: edge phase
  int f4 = (lane & 15) * 4;  // 4 features per lane
  int beg = ptr[i], end = ptr[i + 1];
  float di = dinv[i];
  float a[4] = {};
  int e = beg;
  for (; e + 16 <= end; e += 16) {
    int s0 = ss[e + sub], s1 = ss[e + 4 + sub], s2 = ss[e + 8 + sub], s3 = ss[e + 12 + sub];
    float c0 = dinv[s0], c1 = dinv[s1], c2 = dinv[s2], c3 = dinv[s3];
    ushort4 v0 = *reinterpret_cast<const ushort4*>(h2bf + (size_t)s0 * CDIM + f4);
    ushort4 v1 = *reinterpret_cast<const ushort4*>(h2bf + (size_t)s1 * CDIM + f4);
    ushort4 v2 = *reinterpret_cast<const ushort4*>(h2bf + (size_t)s2 * CDIM + f4);
    ushort4 v3 = *reinterpret_cast<const ushort4*>(h2bf + (size_t)s3 * CDIM + f4);
    a[0] += c0 * bf2f(v0.x) + c1 * bf2f(v1.x) + c2 * bf2f(v2.x) + c3 * bf2f(v3.x);
    a[1] += c0 * bf2f(v0.y) + c1 * bf2f(v1.y) + c2 * bf2f(v2.y) + c3 * bf2f(v3.y);
    a[2] += c0 * bf2f(v0.z) + c1 * bf2f(v1.z) + c2 * bf2f(v2.z) + c3 * bf2f(v3.z);
    a[3] += c0 * bf2f(v0.w) + c1 * bf2f(v1.w) + c2 * bf2f(v2.w) + c3 * bf2f(v3.w);
  }
  for (; e < end; e += 4) {
    int idx = e + sub;
    if (idx < end) {
      int s = ss[idx];
      float c = dinv[s];
      ushort4 v = *reinterpret_cast<const ushort4*>(h2bf + (size_t)s * CDIM + f4);
      a[0] += c * bf2f(v.x); a[1] += c * bf2f(v.y);
      a[2] += c * bf2f(v.z); a[3] += c * bf2f(v.w);
    }
  }
  #pragma unroll
  for (int k = 0; k < 4; ++k) {
    a[k] += __shfl_xor(a[k], 16);
    a[k] += __shfl_xor(a[k], 32);
  }
  if (sub == 0) {
    ushort4 selfv = *reinterpret_cast<const ushort4*>(h2bf + (size_t)i * CDIM + f4);
    float4 vb2 = *reinterpret_cast<const float4*>(b2 + f4);
    float di2 = di * di;
    float4 o;
    o.x = a[0] * di + bf2f(selfv.x) * di2 + vb2.x;
    o.y = a[1] * di + bf2f(selfv.y) * di2 + vb2.y;
    o.z = a[2] * di + bf2f(selfv.z) * di2 + vb2.z;
    o.w = a[3] * di + bf2f(selfv.w) * di2 + vb2.w;
    *reinterpret_cast<float4*>(out + (size_t)i * CDIM + f4) = o;
  }
}

extern "C" void kernel_launch(void* const* d_in, const int* in_sizes, int n_in,
                              void* d_out, int out_size, void* d_ws, size_t ws_size,
                              hipStream_t stream) {
  const float* x     = (const float*)d_in[0];
  const int*   ei    = (const int*)d_in[1];
  const float* W1    = (const float*)d_in[2];
  const float* b1    = (const float*)d_in[3];
  const float* gamma = (const float*)d_in[4];
  const float* beta  = (const float*)d_in[5];
  const float* rm    = (const float*)d_in[6];
  const float* rv    = (const float*)d_in[7];
  const float* W2    = (const float*)d_in[8];
  const float* b2    = (const float*)d_in[9];
  float* out = (float*)d_out;

  const int* src = ei;
  const int* dst = ei + NEDGES;

  char* ws = (char*)d_ws;
  auto alloc = [&](size_t bytes) {
    void* p = ws;
    ws += (bytes + 255) & ~(size_t)255;
    return p;
  };
  unsigned* esort   = (unsigned*)alloc((size_t)NEDGES * 4);
  int*   bh       = (int*)alloc((size_t)NSEGS * NBLK * 4);
  int*   rowpref  = (int*)alloc((size_t)NSEGS * NBLK * 4);
  int*   segtot   = (int*)alloc((size_t)NSEGS * 4);
  int*   segbase  = (int*)alloc(((size_t)NSEGS + 1) * 4);
  int*   ptr      = (int*)alloc(((size_t)NNODES + 1) * 4);
  float* dinv     = (float*)alloc((size_t)NNODES * 4);
  int*   s_sorted = (int*)alloc((size_t)NEDGES * 4);
  unsigned short* xbf    = (unsigned short*)alloc((size_t)NNODES * FIN * 2);  // -> houtHi
  unsigned short* xhHi   = (unsigned short*)alloc((size_t)NNODES * FIN * 2);
  unsigned short* h2bf   = (unsigned short*)alloc((size_t)NNODES * CDIM * 2);
  unsigned short* w1thi  = (unsigned short*)alloc((size_t)HDIM * FIN * 2);
  unsigned short* w1tlo  = (unsigned short*)alloc((size_t)HDIM * FIN * 2);
  unsigned short* w2thi  = (unsigned short*)alloc((size_t)CDIM * HDIM * 2);
  unsigned short* w2tlo  = (unsigned short*)alloc((size_t)CDIM * HDIM * 2);
  float* bn_s = (float*)alloc(HDIM * 4);
  float* bn_t = (float*)alloc(HDIM * 4);

  unsigned short* houtHi = xbf;  // alias: xbf dead after agg_x

  // CSR build (convert + weight-split fused into the low-occupancy passes)
  p1hist_k<<<NBLK + XBLK, 256, 0, stream>>>(dst, x, bh, xbf);
  p1scan_k<<<NSEGS + HDIM + CDIM + 1, 512, 0, stream>>>(
      bh, rowpref, segtot, W1, W2, b1, gamma, beta, rm, rv,
      w1thi, w1tlo, w2thi, w2tlo, bn_s, bn_t);
  segscan_k<<<1, 512, 0, stream>>>(segtot, segbase);
  p1scat_k<<<NBLK, 512, 0, stream>>>(src, dst, rowpref, segbase, esort);
  p2_k<<<NSEGS, 256, 0, stream>>>(esort, segtot, segbase, s_sorted, ptr, dinv);

  // layer 1 reordered: xhat = A_norm*x (bf16), hout = relu(BN(xhat@W1+b1)) in GEMM epilogue
  agg_x_k<<<(NNODES + 3) / 4, 256, 0, stream>>>(ptr, s_sorted, dinv, xbf, xhHi, NNODES);
  gemm_split_k<128, 1><<<dim3((NNODES + 127) / 128, HDIM / 128), 256, 0, stream>>>(
      xhHi, w1thi, w1tlo, houtHi, bn_s, bn_t, NNODES, HDIM, FIN);

  // layer 2: h2 = hout@W2 (2-term, bf16 out only), out = A_norm*h2 + b2
  gemm_split_k<64, 2><<<dim3((NNODES + 127) / 128, 1), 256, 0, stream>>>(
      houtHi, w2thi, w2tlo, h2bf, nullptr, nullptr, NNODES, CDIM, HDIM);
  agg2_k<<<(NNODES + 3) / 4, 256, 0, stream>>>(ptr, s_sorted, dinv, h2bf, b2, out, NNODES);
}